// Round 1
// baseline (8484.107 us; speedup 1.0000x reference)
//
#include <hip/hip_runtime.h>
#include <math.h>

// ---------------- graph prep ----------------

__global__ __launch_bounds__(256) void k_init_deg(float* deg, int n) {
    int i = blockIdx.x * 256 + threadIdx.x;
    if (i < n) deg[i] = 1.0f;   // self-loop weight
}

__global__ __launch_bounds__(256) void k_count_deg(const int* __restrict__ ei,
                                                   float* __restrict__ deg,
                                                   int E, int N) {
    int i = blockIdx.x * 256 + threadIdx.x;
    if (i < E) {
        int d = ei[E + i];      // dst row
        if ((unsigned)d < (unsigned)N) unsafeAtomicAdd(&deg[d], 1.0f);
    }
}

__global__ __launch_bounds__(256) void k_dis(float* deg, int n) {
    int i = blockIdx.x * 256 + threadIdx.x;
    if (i < n) deg[i] = 1.0f / sqrtf(deg[i]);   // deg >= 1 always
}

// ---------------- fused GEMM:  H = X @ W ;  AGG = H*dis^2 + bias ----------------
// K = 128 fixed. BM rows/block, BN = full N. Thread tile TM x 8.
// X-tile staged transposed in LDS: xs[k][r], leading-dim BM+4 (pad: compute
// reads land 2-way on banks = free; transpose writes 16-way but amortized).

template <int BM, int BN, int TM, bool RELU_IN>
__global__ __launch_bounds__(256) void k_gemm_fused(
    const float* __restrict__ X, const float* __restrict__ W,
    const float* __restrict__ bias, const float* __restrict__ dis,
    float* __restrict__ H, float* __restrict__ AGG, int M)
{
    constexpr int K = 128;
    constexpr int TN = 8;
    constexpr int RG = BM / TM;          // row groups
    constexpr int LSTR = BM + 4;
    __shared__ float xs[K * LSTR];

    const int tid = threadIdx.x;
    const int m0 = blockIdx.x * BM;

    // stage X tile (transposed)
    const float4* X4 = (const float4*)X;
    constexpr int NV = BM * (K / 4) / 256;      // float4s per thread
#pragma unroll
    for (int i = 0; i < NV; ++i) {
        int idx = tid + i * 256;
        int r = idx >> 5;                // 32 float4 per row
        int kq = idx & 31;
        float4 v = make_float4(0.f, 0.f, 0.f, 0.f);
        int gr = m0 + r;
        if (gr < M) v = X4[gr * 32 + kq];
        if (RELU_IN) {
            v.x = fmaxf(v.x, 0.f); v.y = fmaxf(v.y, 0.f);
            v.z = fmaxf(v.z, 0.f); v.w = fmaxf(v.w, 0.f);
        }
        int kb = kq * 4;
        xs[(kb + 0) * LSTR + r] = v.x;
        xs[(kb + 1) * LSTR + r] = v.y;
        xs[(kb + 2) * LSTR + r] = v.z;
        xs[(kb + 3) * LSTR + r] = v.w;
    }
    __syncthreads();

    const int rg = tid % RG;
    const int cg = tid / RG;             // BN/8 col groups

    float acc[TM][TN];
#pragma unroll
    for (int j = 0; j < TM; ++j)
#pragma unroll
        for (int c = 0; c < TN; ++c) acc[j][c] = 0.f;

    const float4* W4 = (const float4*)W;
#pragma unroll 4
    for (int k = 0; k < K; ++k) {
        float a[TM];
        if constexpr (TM == 4) {
            float4 av = *(const float4*)&xs[k * LSTR + rg * 4];
            a[0] = av.x; a[1] = av.y; a[2] = av.z; a[3] = av.w;
        } else {
            float2 av = *(const float2*)&xs[k * LSTR + rg * 2];
            a[0] = av.x; a[1] = av.y;
        }
        float4 b0 = W4[k * (BN / 4) + cg * 2];
        float4 b1 = W4[k * (BN / 4) + cg * 2 + 1];
#pragma unroll
        for (int j = 0; j < TM; ++j) {
            acc[j][0] = fmaf(a[j], b0.x, acc[j][0]);
            acc[j][1] = fmaf(a[j], b0.y, acc[j][1]);
            acc[j][2] = fmaf(a[j], b0.z, acc[j][2]);
            acc[j][3] = fmaf(a[j], b0.w, acc[j][3]);
            acc[j][4] = fmaf(a[j], b1.x, acc[j][4]);
            acc[j][5] = fmaf(a[j], b1.y, acc[j][5]);
            acc[j][6] = fmaf(a[j], b1.z, acc[j][6]);
            acc[j][7] = fmaf(a[j], b1.w, acc[j][7]);
        }
    }

    // epilogue: H raw, AGG = H*dis^2 + bias
    const float4* B4 = (const float4*)bias;
    float4 bb0 = B4[cg * 2], bb1 = B4[cg * 2 + 1];
    float4* H4 = (float4*)H;
    float4* A4 = (float4*)AGG;
#pragma unroll
    for (int j = 0; j < TM; ++j) {
        int r = m0 + rg * TM + j;
        if (r < M) {
            float dv = dis[r];
            float s = dv * dv;
            float4 h0 = make_float4(acc[j][0], acc[j][1], acc[j][2], acc[j][3]);
            float4 h1 = make_float4(acc[j][4], acc[j][5], acc[j][6], acc[j][7]);
            H4[r * (BN / 4) + cg * 2]     = h0;
            H4[r * (BN / 4) + cg * 2 + 1] = h1;
            float4 a0 = make_float4(fmaf(h0.x, s, bb0.x), fmaf(h0.y, s, bb0.y),
                                    fmaf(h0.z, s, bb0.z), fmaf(h0.w, s, bb0.w));
            float4 a1 = make_float4(fmaf(h1.x, s, bb1.x), fmaf(h1.y, s, bb1.y),
                                    fmaf(h1.z, s, bb1.z), fmaf(h1.w, s, bb1.w));
            A4[r * (BN / 4) + cg * 2]     = a0;
            A4[r * (BN / 4) + cg * 2 + 1] = a1;
        }
    }
}

// ---------------- edge scatter:  AGG[dst] += H[src] * dis[src]*dis[dst] ----------------
// DQ = D/4 lanes per edge, float4 per lane.

template <int DQ>
__global__ __launch_bounds__(256) void k_scatter(
    const int* __restrict__ ei, const float* __restrict__ dis,
    const float* __restrict__ H, float* __restrict__ AGG, int E, int N)
{
    int gid = blockIdx.x * 256 + threadIdx.x;
    int e = gid / DQ;
    int q = gid % DQ;
    if (e >= E) return;
    int src = ei[e];
    int dst = ei[E + e];
    if ((unsigned)src >= (unsigned)N || (unsigned)dst >= (unsigned)N) return;
    float nrm = dis[src] * dis[dst];
    float4 v = ((const float4*)H)[src * DQ + q];
    float* base = AGG + (size_t)dst * (DQ * 4) + q * 4;
    unsafeAtomicAdd(base + 0, v.x * nrm);
    unsafeAtomicAdd(base + 1, v.y * nrm);
    unsafeAtomicAdd(base + 2, v.z * nrm);
    unsafeAtomicAdd(base + 3, v.w * nrm);
}

// ---------------- mean pool over sorted batch ----------------

__device__ inline int lower_bound(const int* __restrict__ b, int n, int v) {
    int lo = 0, hi = n;
    while (lo < hi) { int m = (lo + hi) >> 1; if (b[m] < v) lo = m + 1; else hi = m; }
    return lo;
}

__global__ __launch_bounds__(256) void k_pool(
    const int* __restrict__ batch, const float* __restrict__ AGG2,
    float* __restrict__ G, int n)
{
    int g = blockIdx.x;
    int start = lower_bound(batch, n, g);
    int end   = lower_bound(batch, n, g + 1);
    int tid = threadIdx.x;
    int f = tid & 63, stripe = tid >> 6;
    float acc = 0.f;
    for (int i = start + stripe; i < end; i += 4)
        acc += AGG2[(size_t)i * 64 + f];
    __shared__ float red[256];
    red[tid] = acc;
    __syncthreads();
    if (tid < 64) {
        float s = red[tid] + red[tid + 64] + red[tid + 128] + red[tid + 192];
        float c = (float)(end - start);
        G[g * 64 + tid] = s / fmaxf(c, 1.0f);
    }
}

// ---------------- classifier: out = G @ Wfc + bfc ----------------

__global__ __launch_bounds__(256) void k_fc(
    const float* __restrict__ G, const float* __restrict__ Wfc,
    const float* __restrict__ bfc, float* __restrict__ out, int ng)
{
    __shared__ float wl[640];
    __shared__ float bl[10];
    int tid = threadIdx.x;
    for (int i = tid; i < 640; i += 256) wl[i] = Wfc[i];
    if (tid < 10) bl[tid] = bfc[tid];
    __syncthreads();
    if (tid >= ng) return;
    float acc[10];
#pragma unroll
    for (int c = 0; c < 10; ++c) acc[c] = bl[c];
    for (int k = 0; k < 64; ++k) {
        float gv = G[tid * 64 + k];
#pragma unroll
        for (int c = 0; c < 10; ++c) acc[c] = fmaf(gv, wl[k * 10 + c], acc[c]);
    }
#pragma unroll
    for (int c = 0; c < 10; ++c) out[tid * 10 + c] = acc[c];
}

// ---------------- launch ----------------

extern "C" void kernel_launch(void* const* d_in, const int* in_sizes, int n_in,
                              void* d_out, int out_size, void* d_ws, size_t ws_size,
                              hipStream_t stream)
{
    const float* x    = (const float*)d_in[0];
    const int*   ei   = (const int*)d_in[1];
    const int*   batch= (const int*)d_in[2];
    const float* W1   = (const float*)d_in[3];
    const float* b1   = (const float*)d_in[4];
    const float* W2   = (const float*)d_in[5];
    const float* b2   = (const float*)d_in[6];
    const float* Wfc  = (const float*)d_in[7];
    const float* bfc  = (const float*)d_in[8];
    float* out = (float*)d_out;

    const int N  = in_sizes[0] / 128;     // 100000
    const int E  = in_sizes[1] / 2;       // 3200000
    const int ng = out_size / 10;         // 256

    float* ws   = (float*)d_ws;
    float* dis  = ws;                       // N (rounded region 102400)
    float* h1   = ws + 102400;              // N*128
    float* agg1 = h1 + 12800000;            // N*128
    float* g    = agg1 + 12800000;          // ng*64
    float* h2   = h1;                       // alias: h1 dead after scatter1
    float* agg2 = h1 + 6400000;             // alias upper half

    // 1. degrees -> dis
    k_init_deg<<<(N + 255) / 256, 256, 0, stream>>>(dis, N);
    k_count_deg<<<(E + 255) / 256, 256, 0, stream>>>(ei, dis, E, N);
    k_dis<<<(N + 255) / 256, 256, 0, stream>>>(dis, N);

    // 2. layer 1: h1 = x@W1 ; agg1 = h1*dis^2 + b1 ; scatter
    k_gemm_fused<64, 128, 4, false><<<(N + 63) / 64, 256, 0, stream>>>(
        x, W1, b1, dis, h1, agg1, N);
    {
        long long work = (long long)E * 32;
        k_scatter<32><<<(int)((work + 255) / 256), 256, 0, stream>>>(
            ei, dis, h1, agg1, E, N);
    }

    // 3. layer 2: h2 = relu(agg1)@W2 ; agg2 = h2*dis^2 + b2 ; scatter
    k_gemm_fused<64, 64, 2, true><<<(N + 63) / 64, 256, 0, stream>>>(
        agg1, W2, b2, dis, h2, agg2, N);
    {
        long long work = (long long)E * 16;
        k_scatter<16><<<(int)((work + 255) / 256), 256, 0, stream>>>(
            ei, dis, h2, agg2, E, N);
    }

    // 4. pool + classifier
    k_pool<<<ng, 256, 0, stream>>>(batch, agg2, g, N);
    k_fc<<<1, 256, 0, stream>>>(g, Wfc, bfc, out, ng);
}

// Round 2
// 1269.525 us; speedup vs baseline: 6.6829x; 6.6829x over previous
//
#include <hip/hip_runtime.h>
#include <math.h>

// ================= CSR build (counting sort of edges by dst) =================

__global__ __launch_bounds__(256) void k_zero_int(int* p, int n) {
    int i = blockIdx.x * 256 + threadIdx.x;
    if (i < n) p[i] = 0;
}

__global__ __launch_bounds__(256) void k_count(const int* __restrict__ ei,
                                               int* __restrict__ cnt,
                                               int E, int N) {
    int i = blockIdx.x * 256 + threadIdx.x;
    if (i < E) {
        int d = ei[E + i];
        if ((unsigned)d < (unsigned)N) atomicAdd(&cnt[d], 1);
    }
}

// chunk sums: one block per 256-element chunk of cnt
__global__ __launch_bounds__(256) void k_chunk_sum(const int* __restrict__ cnt,
                                                   int* __restrict__ chunkSum,
                                                   int N) {
    __shared__ int red[256];
    int t = threadIdx.x;
    int i = blockIdx.x * 256 + t;
    red[t] = (i < N) ? cnt[i] : 0;
    __syncthreads();
    for (int off = 128; off > 0; off >>= 1) {
        if (t < off) red[t] += red[t + off];
        __syncthreads();
    }
    if (t == 0) chunkSum[blockIdx.x] = red[0];
}

// single block: exclusive scan of nchunk (<512) chunk sums -> chunkOff
__global__ __launch_bounds__(512) void k_scan_chunks(const int* __restrict__ chunkSum,
                                                     int* __restrict__ chunkOff,
                                                     int nchunk) {
    __shared__ int sc[512];
    int t = threadIdx.x;
    int v = (t < nchunk) ? chunkSum[t] : 0;
    sc[t] = v;
    __syncthreads();
    for (int off = 1; off < 512; off <<= 1) {
        int u = (t >= off) ? sc[t - off] : 0;
        __syncthreads();
        sc[t] += u;
        __syncthreads();
    }
    if (t < nchunk) chunkOff[t] = sc[t] - v;   // exclusive
}

// per-chunk exclusive scan + chunk offset -> rowptr; also copy into cursor
__global__ __launch_bounds__(256) void k_write_rowptr(const int* __restrict__ cnt,
                                                      const int* __restrict__ chunkOff,
                                                      int* __restrict__ rowptr,
                                                      int* __restrict__ cursor,
                                                      int N, int E) {
    __shared__ int sc[256];
    int t = threadIdx.x;
    int i = blockIdx.x * 256 + t;
    int v = (i < N) ? cnt[i] : 0;
    sc[t] = v;
    __syncthreads();
    for (int off = 1; off < 256; off <<= 1) {
        int u = (t >= off) ? sc[t - off] : 0;
        __syncthreads();
        sc[t] += u;
        __syncthreads();
    }
    if (i < N) {
        int ex = chunkOff[blockIdx.x] + sc[t] - v;
        rowptr[i] = ex;
        cursor[i] = ex;
        if (i == N - 1) rowptr[N] = ex + v;   // == E (all dst in range)
    }
}

__global__ __launch_bounds__(256) void k_fill(const int* __restrict__ ei,
                                              int* __restrict__ cursor,
                                              int* __restrict__ csr,
                                              int E, int N) {
    int i = blockIdx.x * 256 + threadIdx.x;
    if (i < E) {
        int s = ei[i];
        int d = ei[E + i];
        if ((unsigned)d < (unsigned)N) {
            int pos = atomicAdd(&cursor[d], 1);
            csr[pos] = s;
        }
    }
}

__global__ __launch_bounds__(256) void k_dis(const int* __restrict__ rowptr,
                                             float* __restrict__ dis, int n) {
    int i = blockIdx.x * 256 + threadIdx.x;
    if (i < n) {
        float deg = (float)(rowptr[i + 1] - rowptr[i]) + 1.0f;   // + self-loop
        dis[i] = rsqrtf(deg);
    }
}

// ================= GEMM:  H = X @ W  (K = 128 fixed) =================
// X-tile transposed in LDS, thread tile TM x 8, W streamed from L2.

template <int BM, int BN, int TM, bool RELU_IN>
__global__ __launch_bounds__(256) void k_gemm(
    const float* __restrict__ X, const float* __restrict__ W,
    float* __restrict__ H, int M)
{
    constexpr int K = 128;
    constexpr int TN = 8;
    constexpr int RG = BM / TM;
    constexpr int LSTR = BM + 4;
    __shared__ float xs[K * LSTR];

    const int tid = threadIdx.x;
    const int m0 = blockIdx.x * BM;

    const float4* X4 = (const float4*)X;
    constexpr int NV = BM * (K / 4) / 256;
#pragma unroll
    for (int i = 0; i < NV; ++i) {
        int idx = tid + i * 256;
        int r = idx >> 5;
        int kq = idx & 31;
        float4 v = make_float4(0.f, 0.f, 0.f, 0.f);
        int gr = m0 + r;
        if (gr < M) v = X4[gr * 32 + kq];
        if (RELU_IN) {
            v.x = fmaxf(v.x, 0.f); v.y = fmaxf(v.y, 0.f);
            v.z = fmaxf(v.z, 0.f); v.w = fmaxf(v.w, 0.f);
        }
        int kb = kq * 4;
        xs[(kb + 0) * LSTR + r] = v.x;
        xs[(kb + 1) * LSTR + r] = v.y;
        xs[(kb + 2) * LSTR + r] = v.z;
        xs[(kb + 3) * LSTR + r] = v.w;
    }
    __syncthreads();

    const int rg = tid % RG;
    const int cg = tid / RG;

    float acc[TM][TN];
#pragma unroll
    for (int j = 0; j < TM; ++j)
#pragma unroll
        for (int c = 0; c < TN; ++c) acc[j][c] = 0.f;

    const float4* W4 = (const float4*)W;
#pragma unroll 4
    for (int k = 0; k < K; ++k) {
        float a[TM];
        if constexpr (TM == 4) {
            float4 av = *(const float4*)&xs[k * LSTR + rg * 4];
            a[0] = av.x; a[1] = av.y; a[2] = av.z; a[3] = av.w;
        } else {
            float2 av = *(const float2*)&xs[k * LSTR + rg * 2];
            a[0] = av.x; a[1] = av.y;
        }
        float4 b0 = W4[k * (BN / 4) + cg * 2];
        float4 b1 = W4[k * (BN / 4) + cg * 2 + 1];
#pragma unroll
        for (int j = 0; j < TM; ++j) {
            acc[j][0] = fmaf(a[j], b0.x, acc[j][0]);
            acc[j][1] = fmaf(a[j], b0.y, acc[j][1]);
            acc[j][2] = fmaf(a[j], b0.z, acc[j][2]);
            acc[j][3] = fmaf(a[j], b0.w, acc[j][3]);
            acc[j][4] = fmaf(a[j], b1.x, acc[j][4]);
            acc[j][5] = fmaf(a[j], b1.y, acc[j][5]);
            acc[j][6] = fmaf(a[j], b1.z, acc[j][6]);
            acc[j][7] = fmaf(a[j], b1.w, acc[j][7]);
        }
    }

    float4* H4 = (float4*)H;
#pragma unroll
    for (int j = 0; j < TM; ++j) {
        int r = m0 + rg * TM + j;
        if (r < M) {
            H4[r * (BN / 4) + cg * 2] =
                make_float4(acc[j][0], acc[j][1], acc[j][2], acc[j][3]);
            H4[r * (BN / 4) + cg * 2 + 1] =
                make_float4(acc[j][4], acc[j][5], acc[j][6], acc[j][7]);
        }
    }
}

// ====== Aggregate (gather over CSR):  AGG[n] = sum_{src->n} H[src]*dis[src]*dis[n]
//                                              + H[n]*dis[n]^2 + bias ======
// One wave per destination node. VEC = D/64 floats per lane (2 or 1).

template <int VEC>
__global__ __launch_bounds__(256) void k_aggregate(
    const int* __restrict__ rowptr, const int* __restrict__ csr,
    const float* __restrict__ dis, const float* __restrict__ H,
    const float* __restrict__ bias, float* __restrict__ AGG, int N)
{
    int wave = (blockIdx.x * 256 + threadIdx.x) >> 6;
    int lane = threadIdx.x & 63;
    if (wave >= N) return;
    const int n = wave;
    const int s0 = rowptr[n], s1 = rowptr[n + 1];
    const float dn = dis[n];

    float acc0 = 0.f, acc1 = 0.f;
    for (int e = s0; e < s1; ++e) {
        int src = csr[e];                       // broadcast across wave
        float nrm = dis[src] * dn;              // broadcast
        if constexpr (VEC == 2) {
            float2 v = ((const float2*)H)[src * 64 + lane];
            acc0 = fmaf(v.x, nrm, acc0);
            acc1 = fmaf(v.y, nrm, acc1);
        } else {
            acc0 = fmaf(H[src * 64 + lane], nrm, acc0);
        }
    }

    float s = dn * dn;
    if constexpr (VEC == 2) {
        float2 hv = ((const float2*)H)[n * 64 + lane];
        float2 bv = ((const float2*)bias)[lane];
        float2 o;
        o.x = fmaf(hv.x, s, acc0) + bv.x;
        o.y = fmaf(hv.y, s, acc1) + bv.y;
        ((float2*)AGG)[n * 64 + lane] = o;
    } else {
        float hv = H[n * 64 + lane];
        AGG[n * 64 + lane] = fmaf(hv, s, acc0) + bias[lane];
    }
}

// ================= mean pool over sorted batch =================

__device__ inline int lower_bound(const int* __restrict__ b, int n, int v) {
    int lo = 0, hi = n;
    while (lo < hi) { int m = (lo + hi) >> 1; if (b[m] < v) lo = m + 1; else hi = m; }
    return lo;
}

__global__ __launch_bounds__(256) void k_pool(
    const int* __restrict__ batch, const float* __restrict__ AGG2,
    float* __restrict__ G, int n)
{
    int g = blockIdx.x;
    int start = lower_bound(batch, n, g);
    int end   = lower_bound(batch, n, g + 1);
    int tid = threadIdx.x;
    int f = tid & 63, stripe = tid >> 6;
    float acc = 0.f;
    for (int i = start + stripe; i < end; i += 4)
        acc += AGG2[(size_t)i * 64 + f];
    __shared__ float red[256];
    red[tid] = acc;
    __syncthreads();
    if (tid < 64) {
        float s = red[tid] + red[tid + 64] + red[tid + 128] + red[tid + 192];
        float c = (float)(end - start);
        G[g * 64 + tid] = s / fmaxf(c, 1.0f);
    }
}

// ================= classifier =================

__global__ __launch_bounds__(256) void k_fc(
    const float* __restrict__ G, const float* __restrict__ Wfc,
    const float* __restrict__ bfc, float* __restrict__ out, int ng)
{
    __shared__ float wl[640];
    __shared__ float bl[10];
    int tid = threadIdx.x;
    for (int i = tid; i < 640; i += 256) wl[i] = Wfc[i];
    if (tid < 10) bl[tid] = bfc[tid];
    __syncthreads();
    if (tid >= ng) return;
    float acc[10];
#pragma unroll
    for (int c = 0; c < 10; ++c) acc[c] = bl[c];
    for (int k = 0; k < 64; ++k) {
        float gv = G[tid * 64 + k];
#pragma unroll
        for (int c = 0; c < 10; ++c) acc[c] = fmaf(gv, wl[k * 10 + c], acc[c]);
    }
#pragma unroll
    for (int c = 0; c < 10; ++c) out[tid * 10 + c] = acc[c];
}

// ================= launch =================

extern "C" void kernel_launch(void* const* d_in, const int* in_sizes, int n_in,
                              void* d_out, int out_size, void* d_ws, size_t ws_size,
                              hipStream_t stream)
{
    const float* x    = (const float*)d_in[0];
    const int*   ei   = (const int*)d_in[1];
    const int*   batch= (const int*)d_in[2];
    const float* W1   = (const float*)d_in[3];
    const float* b1   = (const float*)d_in[4];
    const float* W2   = (const float*)d_in[5];
    const float* b2   = (const float*)d_in[6];
    const float* Wfc  = (const float*)d_in[7];
    const float* bfc  = (const float*)d_in[8];
    float* out = (float*)d_out;

    const int N  = in_sizes[0] / 128;     // 100000
    const int E  = in_sizes[1] / 2;       // 3200000
    const int ng = out_size / 10;         // 256

    const int NCHUNK = (N + 255) / 256;   // 391

    // ---- workspace layout ----
    int*   rowptr = (int*)d_ws;                 // N+1  (pad region 102400)
    int*   cursor = rowptr + 102400;            // N    (also used as cnt)
    int*   csr    = cursor + 102400;            // E
    int*   chunk  = csr + E;                    // [0..511] sums, [512..1023] offs
    float* dis    = (float*)(chunk + 1024);     // N (pad 102400)
    float* h1     = dis + 102400;               // N*128
    float* agg1   = h1 + 12800000;              // N*128
    float* g      = agg1 + 12800000;            // ng*64
    float* h2     = h1;                         // alias (h1 dead after agg1 built? see order)
    float* agg2   = h1 + 6400000;               // alias upper half of h1

    // ---- CSR build ----
    k_zero_int<<<(N + 255) / 256, 256, 0, stream>>>(cursor, N);
    k_count<<<(E + 255) / 256, 256, 0, stream>>>(ei, cursor, E, N);
    k_chunk_sum<<<NCHUNK, 256, 0, stream>>>(cursor, chunk, N);
    k_scan_chunks<<<1, 512, 0, stream>>>(chunk, chunk + 512, NCHUNK);
    k_write_rowptr<<<NCHUNK, 256, 0, stream>>>(cursor, chunk + 512, rowptr, cursor, N, E);
    k_fill<<<(E + 255) / 256, 256, 0, stream>>>(ei, cursor, csr, E, N);
    k_dis<<<(N + 255) / 256, 256, 0, stream>>>(rowptr, dis, N);

    // ---- layer 1: h1 = x@W1 ; agg1 = gather + self + b1 ----
    k_gemm<64, 128, 4, false><<<(N + 63) / 64, 256, 0, stream>>>(x, W1, h1, N);
    k_aggregate<2><<<(N + 3) / 4, 256, 0, stream>>>(rowptr, csr, dis, h1, b1, agg1, N);

    // ---- layer 2: h2 = relu(agg1)@W2 ; agg2 = gather + self + b2 ----
    k_gemm<64, 64, 2, true><<<(N + 63) / 64, 256, 0, stream>>>(agg1, W2, h2, N);
    k_aggregate<1><<<(N + 3) / 4, 256, 0, stream>>>(rowptr, csr, dis, h2, b2, agg2, N);

    // ---- pool + classifier ----
    k_pool<<<ng, 256, 0, stream>>>(batch, agg2, g, N);
    k_fc<<<1, 256, 0, stream>>>(g, Wfc, bfc, out, ng);
}

// Round 3
// 933.801 us; speedup vs baseline: 9.0856x; 1.3595x over previous
//
#include <hip/hip_runtime.h>
#include <math.h>

// ================= CSR build (counting sort of edges by dst) =================

__global__ __launch_bounds__(256) void k_zero_int(int* p, int n) {
    int i = blockIdx.x * 256 + threadIdx.x;
    if (i < n) p[i] = 0;
}

__global__ __launch_bounds__(256) void k_count(const int* __restrict__ ei,
                                               int* __restrict__ cnt,
                                               int E, int N) {
    int i = blockIdx.x * 256 + threadIdx.x;
    if (i < E) {
        int d = ei[E + i];
        if ((unsigned)d < (unsigned)N) atomicAdd(&cnt[d], 1);
    }
}

__global__ __launch_bounds__(256) void k_chunk_sum(const int* __restrict__ cnt,
                                                   int* __restrict__ chunkSum,
                                                   int N) {
    __shared__ int red[256];
    int t = threadIdx.x;
    int i = blockIdx.x * 256 + t;
    red[t] = (i < N) ? cnt[i] : 0;
    __syncthreads();
    for (int off = 128; off > 0; off >>= 1) {
        if (t < off) red[t] += red[t + off];
        __syncthreads();
    }
    if (t == 0) chunkSum[blockIdx.x] = red[0];
}

__global__ __launch_bounds__(512) void k_scan_chunks(const int* __restrict__ chunkSum,
                                                     int* __restrict__ chunkOff,
                                                     int nchunk) {
    __shared__ int sc[512];
    int t = threadIdx.x;
    int v = (t < nchunk) ? chunkSum[t] : 0;
    sc[t] = v;
    __syncthreads();
    for (int off = 1; off < 512; off <<= 1) {
        int u = (t >= off) ? sc[t - off] : 0;
        __syncthreads();
        sc[t] += u;
        __syncthreads();
    }
    if (t < nchunk) chunkOff[t] = sc[t] - v;   // exclusive
}

__global__ __launch_bounds__(256) void k_write_rowptr(const int* __restrict__ cnt,
                                                      const int* __restrict__ chunkOff,
                                                      int* __restrict__ rowptr,
                                                      int* __restrict__ cursor,
                                                      int N, int E) {
    __shared__ int sc[256];
    int t = threadIdx.x;
    int i = blockIdx.x * 256 + t;
    int v = (i < N) ? cnt[i] : 0;
    sc[t] = v;
    __syncthreads();
    for (int off = 1; off < 256; off <<= 1) {
        int u = (t >= off) ? sc[t - off] : 0;
        __syncthreads();
        sc[t] += u;
        __syncthreads();
    }
    if (i < N) {
        int ex = chunkOff[blockIdx.x] + sc[t] - v;
        rowptr[i] = ex;
        cursor[i] = ex;
        if (i == N - 1) rowptr[N] = ex + v;
    }
}

__global__ __launch_bounds__(256) void k_fill(const int* __restrict__ ei,
                                              int* __restrict__ cursor,
                                              int* __restrict__ csr,
                                              int E, int N) {
    int i = blockIdx.x * 256 + threadIdx.x;
    if (i < E) {
        int s = ei[i];
        int d = ei[E + i];
        if ((unsigned)d < (unsigned)N) {
            int pos = atomicAdd(&cursor[d], 1);
            csr[pos] = s;
        }
    }
}

__global__ __launch_bounds__(256) void k_dis(const int* __restrict__ rowptr,
                                             float* __restrict__ dis, int n) {
    int i = blockIdx.x * 256 + threadIdx.x;
    if (i < n) {
        float deg = (float)(rowptr[i + 1] - rowptr[i]) + 1.0f;   // + self-loop
        dis[i] = rsqrtf(deg);
    }
}

// ================= GEMM:  Hs = (X @ W) * dis[row]   (K = 128 fixed) =================

template <int BM, int BN, int TM, bool RELU_IN>
__global__ __launch_bounds__(256) void k_gemm(
    const float* __restrict__ X, const float* __restrict__ W,
    const float* __restrict__ dis, float* __restrict__ Hs, int M)
{
    constexpr int K = 128;
    constexpr int TN = 8;
    constexpr int RG = BM / TM;
    constexpr int LSTR = BM + 4;
    __shared__ float xs[K * LSTR];

    const int tid = threadIdx.x;
    const int m0 = blockIdx.x * BM;

    const float4* X4 = (const float4*)X;
    constexpr int NV = BM * (K / 4) / 256;
#pragma unroll
    for (int i = 0; i < NV; ++i) {
        int idx = tid + i * 256;
        int r = idx >> 5;
        int kq = idx & 31;
        float4 v = make_float4(0.f, 0.f, 0.f, 0.f);
        int gr = m0 + r;
        if (gr < M) v = X4[gr * 32 + kq];
        if (RELU_IN) {
            v.x = fmaxf(v.x, 0.f); v.y = fmaxf(v.y, 0.f);
            v.z = fmaxf(v.z, 0.f); v.w = fmaxf(v.w, 0.f);
        }
        int kb = kq * 4;
        xs[(kb + 0) * LSTR + r] = v.x;
        xs[(kb + 1) * LSTR + r] = v.y;
        xs[(kb + 2) * LSTR + r] = v.z;
        xs[(kb + 3) * LSTR + r] = v.w;
    }
    __syncthreads();

    const int rg = tid % RG;
    const int cg = tid / RG;

    float acc[TM][TN];
#pragma unroll
    for (int j = 0; j < TM; ++j)
#pragma unroll
        for (int c = 0; c < TN; ++c) acc[j][c] = 0.f;

    const float4* W4 = (const float4*)W;
#pragma unroll 4
    for (int k = 0; k < K; ++k) {
        float a[TM];
        if constexpr (TM == 4) {
            float4 av = *(const float4*)&xs[k * LSTR + rg * 4];
            a[0] = av.x; a[1] = av.y; a[2] = av.z; a[3] = av.w;
        } else {
            float2 av = *(const float2*)&xs[k * LSTR + rg * 2];
            a[0] = av.x; a[1] = av.y;
        }
        float4 b0 = W4[k * (BN / 4) + cg * 2];
        float4 b1 = W4[k * (BN / 4) + cg * 2 + 1];
#pragma unroll
        for (int j = 0; j < TM; ++j) {
            acc[j][0] = fmaf(a[j], b0.x, acc[j][0]);
            acc[j][1] = fmaf(a[j], b0.y, acc[j][1]);
            acc[j][2] = fmaf(a[j], b0.z, acc[j][2]);
            acc[j][3] = fmaf(a[j], b0.w, acc[j][3]);
            acc[j][4] = fmaf(a[j], b1.x, acc[j][4]);
            acc[j][5] = fmaf(a[j], b1.y, acc[j][5]);
            acc[j][6] = fmaf(a[j], b1.z, acc[j][6]);
            acc[j][7] = fmaf(a[j], b1.w, acc[j][7]);
        }
    }

    float4* H4 = (float4*)Hs;
#pragma unroll
    for (int j = 0; j < TM; ++j) {
        int r = m0 + rg * TM + j;
        if (r < M) {
            float dv = dis[r];
            H4[r * (BN / 4) + cg * 2] =
                make_float4(acc[j][0] * dv, acc[j][1] * dv, acc[j][2] * dv, acc[j][3] * dv);
            H4[r * (BN / 4) + cg * 2 + 1] =
                make_float4(acc[j][4] * dv, acc[j][5] * dv, acc[j][6] * dv, acc[j][7] * dv);
        }
    }
}

// ====== Aggregate:  AGG[n] = dis[n]*(sum_{src->n} Hs[src] + Hs[n]) + bias ======
// One wave per node. VEC = D/64 floats per lane. Edge loop unrolled x8 with
// independent accumulator sets for memory-level parallelism.

template <int VEC>
__global__ __launch_bounds__(256) void k_aggregate(
    const int* __restrict__ rowptr, const int* __restrict__ csr,
    const float* __restrict__ dis, const float* __restrict__ Hs,
    const float* __restrict__ bias, float* __restrict__ AGG, int N)
{
    int n = (blockIdx.x * 256 + threadIdx.x) >> 6;
    int lane = threadIdx.x & 63;
    if (n >= N) return;
    int e = rowptr[n];
    const int s1 = rowptr[n + 1];
    const float dn = dis[n];
    const float2* H2 = (const float2*)Hs;

    float a0 = 0.f, a1 = 0.f, b0 = 0.f, b1 = 0.f;
    float c0 = 0.f, c1 = 0.f, d0 = 0.f, d1 = 0.f;

    for (; e + 8 <= s1; e += 8) {
        int i0 = csr[e + 0], i1 = csr[e + 1], i2 = csr[e + 2], i3 = csr[e + 3];
        int i4 = csr[e + 4], i5 = csr[e + 5], i6 = csr[e + 6], i7 = csr[e + 7];
        if constexpr (VEC == 2) {
            float2 v0 = H2[i0 * 64 + lane], v1 = H2[i1 * 64 + lane];
            float2 v2 = H2[i2 * 64 + lane], v3 = H2[i3 * 64 + lane];
            float2 v4 = H2[i4 * 64 + lane], v5 = H2[i5 * 64 + lane];
            float2 v6 = H2[i6 * 64 + lane], v7 = H2[i7 * 64 + lane];
            a0 += v0.x + v4.x; a1 += v0.y + v4.y;
            b0 += v1.x + v5.x; b1 += v1.y + v5.y;
            c0 += v2.x + v6.x; c1 += v2.y + v6.y;
            d0 += v3.x + v7.x; d1 += v3.y + v7.y;
        } else {
            a0 += Hs[i0 * 64 + lane] + Hs[i4 * 64 + lane];
            b0 += Hs[i1 * 64 + lane] + Hs[i5 * 64 + lane];
            c0 += Hs[i2 * 64 + lane] + Hs[i6 * 64 + lane];
            d0 += Hs[i3 * 64 + lane] + Hs[i7 * 64 + lane];
        }
    }
    for (; e < s1; ++e) {
        int i0 = csr[e];
        if constexpr (VEC == 2) {
            float2 v = H2[i0 * 64 + lane];
            a0 += v.x; a1 += v.y;
        } else {
            a0 += Hs[i0 * 64 + lane];
        }
    }

    if constexpr (VEC == 2) {
        float2 self = H2[n * 64 + lane];
        float2 bv = ((const float2*)bias)[lane];
        float2 o;
        o.x = fmaf(dn, (a0 + b0) + (c0 + d0) + self.x, bv.x);
        o.y = fmaf(dn, (a1 + b1) + (c1 + d1) + self.y, bv.y);
        ((float2*)AGG)[n * 64 + lane] = o;
    } else {
        float self = Hs[n * 64 + lane];
        AGG[n * 64 + lane] = fmaf(dn, (a0 + b0) + (c0 + d0) + self, bias[lane]);
    }
}

// ================= mean pool over sorted batch =================

__device__ inline int lower_bound(const int* __restrict__ b, int n, int v) {
    int lo = 0, hi = n;
    while (lo < hi) { int m = (lo + hi) >> 1; if (b[m] < v) lo = m + 1; else hi = m; }
    return lo;
}

__global__ __launch_bounds__(256) void k_pool(
    const int* __restrict__ batch, const float* __restrict__ AGG2,
    float* __restrict__ G, int n)
{
    int g = blockIdx.x;
    int start = lower_bound(batch, n, g);
    int end   = lower_bound(batch, n, g + 1);
    int tid = threadIdx.x;
    int f = tid & 63, stripe = tid >> 6;
    float acc = 0.f;
    for (int i = start + stripe; i < end; i += 4)
        acc += AGG2[(size_t)i * 64 + f];
    __shared__ float red[256];
    red[tid] = acc;
    __syncthreads();
    if (tid < 64) {
        float s = red[tid] + red[tid + 64] + red[tid + 128] + red[tid + 192];
        float c = (float)(end - start);
        G[g * 64 + tid] = s / fmaxf(c, 1.0f);
    }
}

// ================= classifier =================

__global__ __launch_bounds__(256) void k_fc(
    const float* __restrict__ G, const float* __restrict__ Wfc,
    const float* __restrict__ bfc, float* __restrict__ out, int ng)
{
    __shared__ float wl[640];
    __shared__ float bl[10];
    int tid = threadIdx.x;
    for (int i = tid; i < 640; i += 256) wl[i] = Wfc[i];
    if (tid < 10) bl[tid] = bfc[tid];
    __syncthreads();
    if (tid >= ng) return;
    float acc[10];
#pragma unroll
    for (int c = 0; c < 10; ++c) acc[c] = bl[c];
    for (int k = 0; k < 64; ++k) {
        float gv = G[tid * 64 + k];
#pragma unroll
        for (int c = 0; c < 10; ++c) acc[c] = fmaf(gv, wl[k * 10 + c], acc[c]);
    }
#pragma unroll
    for (int c = 0; c < 10; ++c) out[tid * 10 + c] = acc[c];
}

// ================= launch =================

extern "C" void kernel_launch(void* const* d_in, const int* in_sizes, int n_in,
                              void* d_out, int out_size, void* d_ws, size_t ws_size,
                              hipStream_t stream)
{
    const float* x    = (const float*)d_in[0];
    const int*   ei   = (const int*)d_in[1];
    const int*   batch= (const int*)d_in[2];
    const float* W1   = (const float*)d_in[3];
    const float* b1   = (const float*)d_in[4];
    const float* W2   = (const float*)d_in[5];
    const float* b2   = (const float*)d_in[6];
    const float* Wfc  = (const float*)d_in[7];
    const float* bfc  = (const float*)d_in[8];
    float* out = (float*)d_out;

    const int N  = in_sizes[0] / 128;     // 100000
    const int E  = in_sizes[1] / 2;       // 3200000
    const int ng = out_size / 10;         // 256

    const int NCHUNK = (N + 255) / 256;   // 391

    // ---- workspace layout ----
    int*   rowptr = (int*)d_ws;                 // N+1  (pad region 102400)
    int*   cursor = rowptr + 102400;            // N    (also used as cnt)
    int*   csr    = cursor + 102400;            // E
    int*   chunk  = csr + E;                    // [0..511] sums, [512..1023] offs
    float* dis    = (float*)(chunk + 1024);     // N (pad 102400)
    float* h1     = dis + 102400;               // N*128 (Hs, layer 1)
    float* agg1   = h1 + 12800000;              // N*128
    float* g      = agg1 + 12800000;            // ng*64
    float* h2     = h1;                         // alias: h1 dead after agg1
    float* agg2   = h1 + 6400000;               // alias upper half of h1

    // ---- CSR build ----
    k_zero_int<<<(N + 255) / 256, 256, 0, stream>>>(cursor, N);
    k_count<<<(E + 255) / 256, 256, 0, stream>>>(ei, cursor, E, N);
    k_chunk_sum<<<NCHUNK, 256, 0, stream>>>(cursor, chunk, N);
    k_scan_chunks<<<1, 512, 0, stream>>>(chunk, chunk + 512, NCHUNK);
    k_write_rowptr<<<NCHUNK, 256, 0, stream>>>(cursor, chunk + 512, rowptr, cursor, N, E);
    k_fill<<<(E + 255) / 256, 256, 0, stream>>>(ei, cursor, csr, E, N);
    k_dis<<<(N + 255) / 256, 256, 0, stream>>>(rowptr, dis, N);

    // ---- layer 1 ----
    k_gemm<64, 128, 4, false><<<(N + 63) / 64, 256, 0, stream>>>(x, W1, dis, h1, N);
    k_aggregate<2><<<(N + 3) / 4, 256, 0, stream>>>(rowptr, csr, dis, h1, b1, agg1, N);

    // ---- layer 2 ----
    k_gemm<64, 64, 2, true><<<(N + 63) / 64, 256, 0, stream>>>(agg1, W2, dis, h2, N);
    k_aggregate<1><<<(N + 3) / 4, 256, 0, stream>>>(rowptr, csr, dis, h2, b2, agg2, N);

    // ---- pool + classifier ----
    k_pool<<<ng, 256, 0, stream>>>(batch, agg2, g, N);
    k_fc<<<1, 256, 0, stream>>>(g, Wfc, bfc, out, ng);
}